// Round 7
// baseline (170.292 us; speedup 1.0000x reference)
//
#include <hip/hip_runtime.h>
#include <hip/hip_fp16.h>
#include <math.h>

// ---------------- problem constants ----------------
// x: (16, 2048, 64) f32  -> out: (16, 2048, 64, 5) f32
// scales = {1,27,76,167,336}; morlet int_psi, n=1024, [-8,8]
#define NB    16
#define T     2048
#define NC    64
#define NROWS (NB*NC)     // 1024
#define PADL2 2696        // left zero-pad (halves), mult of 8
#define XSH_N 7600        // 2696+2048+right pad; covers unclamped depth-5 prefetch (max idx 7592)

// Unified global-k chunk axis: chunk c covers k in [32c, 32c+32), c in [0,169).
// k = b + i + posoff, posoff = 2695-8s; k_min=posoff, k_max=8s+2711.
// Exec order: largest scale first (nested ranges -> alive set is always a prefix).
//   sl:      0      1      2      3      4
//   scale:   336    167    76     27     1
//   CLO:     0      42     65     77     83
//   KS2:     5408   2720   1248   480    64     (=32*NCH, W row stride)
//   WOFF:    0      86528  130048 150016 157696 (halves; total 158720 = 19840 uint4)
//   outslot: 4      3      2      1      0      (output s-axis is ascending scale)
#define WTOT_U4 19840

// ws layout (bytes):
//   0        : __half W[158720]                    (~310 KB)
//   512 KB   : __half xT[1024][2048]               (4 MB)
#define WS_XT    (1u<<19)

typedef _Float16 half8  __attribute__((ext_vector_type(8)));
typedef float    f32x4  __attribute__((ext_vector_type(4)));

// ---------------- kernel 1: fused W-build (block 0) + transpose (blocks 1..128) ----------------
// init: replicates reference float64 arithmetic EXACTLY (rounds 1/2/4 verified):
//   t = linspace(-8,8,1024); step = t[1]-t[0]  ((-8+16/1023)+8 roundtrip!)
//   j_i = int64(i/(s*step)); taps g_i over i in [0,L], L=16s+1:
//   g_0=+sq*k[0]; g_i=sq*(k[j_i]-k[j_{i-1}]); g_L=-sq*k[j_{L-1}];  sq=sqrt(s)
//   Scatter: W[sl][b][ b + i + posoff - 32*CLO[sl] ] = g_i  for b in [0,16).
// transpose: x(n,t,c) -> xT[(n*64+c)][t] as fp16; 4 tiles per block (1024 thr).
__global__ __launch_bounds__(1024) void cwt_prep(const float* __restrict__ x,
                                                 __half* __restrict__ xT,
                                                 __half* __restrict__ W) {
    __shared__ double ps[1024];
    __shared__ double sc[1024];
    __shared__ float  k32[1024];
    __shared__ float  tile4[4][64 * 65];
    const int tid = threadIdx.x;

    if (blockIdx.x == 0) {
        uint4* W4 = (uint4*)W;
        const uint4 z = make_uint4(0u, 0u, 0u, 0u);
        for (int i = tid; i < WTOT_U4; i += 1024) W4[i] = z;

        const double delta = 16.0 / 1023.0;
        double t = (tid == 1023) ? 8.0 : (-8.0 + delta * (double)tid);
        ps[tid] = exp(-0.5 * t * t) * cos(5.0 * t);
        __syncthreads();

        double* a = ps; double* b = sc;
        for (int off = 1; off < 1024; off <<= 1) {
            double v = a[tid];
            if (tid >= off) v += a[tid - off];
            b[tid] = v;
            __syncthreads();
            double* tmp = a; a = b; b = tmp;
        }
        const double step = ((-8.0 + delta) + 8.0);   // NOT exactly 16/1023
        k32[tid] = (float)(a[tid] * step);
        __syncthreads();

        constexpr int SCe[5]   = {336, 167, 76, 27, 1};
        constexpr int KS2[5]   = {5408, 2720, 1248, 480, 64};
        constexpr int WOFFe[5] = {0, 86528, 130048, 150016, 157696};
        constexpr int CLOe[5]  = {0, 42, 65, 77, 83};
        for (int sl = 0; sl < 5; ++sl) {
            const int s = SCe[sl];
            const int L = 16 * s + 1;
            const double c = (double)s * step;
            const float sq = (float)sqrt((double)s);
            const int posoff = PADL2 - 8 * s - 1;
            const int kb0 = posoff - 32 * CLOe[sl];
            __half* wb = W + WOFFe[sl];
            const int Ks = KS2[sl];
            for (int i = tid; i <= L; i += 1024) {
                float g; bool wr = true;
                if (i == 0) {
                    g = sq * k32[0];
                } else if (i == L) {
                    long long jl = (long long)((double)(L - 1) / c);
                    if (jl > 1023) jl = 1023;
                    g = -sq * k32[jl];
                } else {
                    long long j1 = (long long)((double)i / c);
                    long long j0 = (long long)((double)(i - 1) / c);
                    if (j1 > 1023) j1 = 1023;
                    if (j0 > 1023) j0 = 1023;
                    wr = (j1 > j0);
                    g = sq * (k32[j1] - k32[j0]);
                }
                if (wr) {
                    const __half hg = __float2half(g);
                    const int kb = kb0 + i;
                    #pragma unroll
                    for (int bb = 0; bb < 16; ++bb)
                        wb[bb * Ks + kb + bb] = hg;
                }
            }
        }
    } else {
        const int g    = tid >> 8;                // 0..3: tile within block
        const int t256 = tid & 255;
        const int ti   = (blockIdx.x - 1) * 4 + g;  // 0..511
        const int n    = ti >> 5;
        const int t0   = (ti & 31) << 6;
        float* tl = tile4[g];

        const float4* src = (const float4*)(x + ((size_t)(n * T + t0)) * NC);
        #pragma unroll
        for (int k = 0; k < 4; ++k) {
            float4 v = src[t256 + 256 * k];
            const int flat = (t256 + 256 * k) * 4;
            const int tt = flat >> 6, c = flat & 63;
            tl[tt * 65 + c + 0] = v.x;
            tl[tt * 65 + c + 1] = v.y;
            tl[tt * 65 + c + 2] = v.z;
            tl[tt * 65 + c + 3] = v.w;
        }
        __syncthreads();
        const int lane = t256 & 63, w4 = t256 >> 6;
        for (int cc = w4; cc < 64; cc += 4) {
            xT[((size_t)(n * 64 + cc)) * T + t0 + lane] = __float2half(tl[lane * 65 + cc]);
        }
    }
}

// ---------------- kernel 2: Toeplitz-block MFMA conv, software-pipelined, fused epilogue ----------------
// Out_sl[16A+b] = sum_k W_sl[b][k-32*CLO] * xsh[16A+k].
// Block = 1 row (n,c), 2 waves x N=64 cols (4 B-tiles). Depth-D modulo pipeline
// over chunks; A-frags from global W (L1/L2-resident), B-frags from LDS signal.
// Unclamped prefetch overruns <= 2*DEPTH-1 chunks: xsh padded to 7600, W reads
// spill into the next scale's block (in-bounds, discarded).
// Epilogue writes final f32 out[n][t][c][s] directly: per (row,t) the 5 scale
// values are contiguous (20 B) -> 5 dword stores, no fix kernel, no outT.
template<int N, int DEPTH>
__device__ __forceinline__ void conv_seg(int c0, int c1,
                                         const _Float16* __restrict__ xb,
                                         const _Float16* const (&ap)[5],
                                         f32x4 (&acc)[5][4]) {
    half8 A[DEPTH][N];
    half8 B[DEPTH][4];
    #pragma unroll
    for (int d = 0; d < DEPTH; ++d) {
        const int ko = (c0 + d) << 5;
        #pragma unroll
        for (int sl = 0; sl < N; ++sl) A[d][sl] = *(const half8*)(ap[sl] + ko);
        #pragma unroll
        for (int j = 0; j < 4; ++j)   B[d][j]  = *(const half8*)(xb + 256 * j + ko);
    }
    int c = c0;
    for (; c + DEPTH <= c1; c += DEPTH) {
        #pragma unroll
        for (int d = 0; d < DEPTH; ++d) {
            #pragma unroll
            for (int sl = 0; sl < N; ++sl) {
                acc[sl][0] = __builtin_amdgcn_mfma_f32_16x16x32_f16(A[d][sl], B[d][0], acc[sl][0], 0, 0, 0);
                acc[sl][1] = __builtin_amdgcn_mfma_f32_16x16x32_f16(A[d][sl], B[d][1], acc[sl][1], 0, 0, 0);
                acc[sl][2] = __builtin_amdgcn_mfma_f32_16x16x32_f16(A[d][sl], B[d][2], acc[sl][2], 0, 0, 0);
                acc[sl][3] = __builtin_amdgcn_mfma_f32_16x16x32_f16(A[d][sl], B[d][3], acc[sl][3], 0, 0, 0);
            }
            const int ko = (c + DEPTH + d) << 5;   // prefetch (unclamped, memory-safe)
            #pragma unroll
            for (int sl = 0; sl < N; ++sl) A[d][sl] = *(const half8*)(ap[sl] + ko);
            #pragma unroll
            for (int j = 0; j < 4; ++j)   B[d][j]  = *(const half8*)(xb + 256 * j + ko);
        }
    }
    // tail: r = c1-c in [0, DEPTH); slots d<r hold valid chunks c+d
    #pragma unroll
    for (int d = 0; d < DEPTH; ++d) {
        if (d < c1 - c) {
            #pragma unroll
            for (int sl = 0; sl < N; ++sl) {
                acc[sl][0] = __builtin_amdgcn_mfma_f32_16x16x32_f16(A[d][sl], B[d][0], acc[sl][0], 0, 0, 0);
                acc[sl][1] = __builtin_amdgcn_mfma_f32_16x16x32_f16(A[d][sl], B[d][1], acc[sl][1], 0, 0, 0);
                acc[sl][2] = __builtin_amdgcn_mfma_f32_16x16x32_f16(A[d][sl], B[d][2], acc[sl][2], 0, 0, 0);
                acc[sl][3] = __builtin_amdgcn_mfma_f32_16x16x32_f16(A[d][sl], B[d][3], acc[sl][3], 0, 0, 0);
            }
        }
    }
}

__global__ __launch_bounds__(128, 2) void cwt_conv_mfma(const __half* __restrict__ xT,
                                                        const __half* __restrict__ Wg,
                                                        float* __restrict__ out) {
    constexpr int KS2[5]   = {5408, 2720, 1248, 480, 64};
    constexpr int WOFFe[5] = {0, 86528, 130048, 150016, 157696};
    constexpr int CLOe[5]  = {0, 42, 65, 77, 83};

    __shared__ _Float16 xsh[XSH_N];               // 15200 B
    const int tid  = threadIdx.x;
    const int row  = blockIdx.x;
    const int nidx = row >> 6;                    // batch n
    const int cidx = row & 63;                    // channel c
    const int lane = tid & 63;
    const int w    = tid >> 6;                    // wave 0/1: A-cols [64w, 64w+64)
    const int mcol = lane & 15;                   // A-frag: W row b;  B-frag: col n
    const int grp  = lane >> 4;                   // k-subgroup

    // ---- stage padded signal row (fp16) ----
    {
        uint4* x4 = (uint4*)xsh;
        const uint4 z = make_uint4(0u, 0u, 0u, 0u);
        for (int i = tid; i < XSH_N / 8; i += 128)
            if (i < PADL2 / 8 || i >= (PADL2 + T) / 8) x4[i] = z;
        const uint4* src = (const uint4*)(xT + (size_t)row * T);
        x4[PADL2 / 8 + tid] = src[tid];
        x4[PADL2 / 8 + 128 + tid] = src[128 + tid];
    }
    __syncthreads();

    // per-lane operand bases
    const _Float16* xb = xsh + 1024 * w + 16 * mcol + 8 * grp;  // tiles at +0,+256,+512,+768
    const _Float16* ap[5];
    #pragma unroll
    for (int sl = 0; sl < 5; ++sl)
        ap[sl] = (const _Float16*)Wg + WOFFe[sl] + mcol * KS2[sl] + 8 * grp
                 - (CLOe[sl] << 5);

    f32x4 acc[5][4];
    #pragma unroll
    for (int sl = 0; sl < 5; ++sl)
        #pragma unroll
        for (int j = 0; j < 4; ++j)
            acc[sl][j] = (f32x4){0.f, 0.f, 0.f, 0.f};

    // constant-alive-count segments over the unified chunk axis
    // alive: 336:[0,169) 167:[42,127) 76:[65,104) 27:[77,92) 1:[83,85)
    conv_seg<1,5>(  0,  42, xb, ap, acc);
    conv_seg<2,3>( 42,  65, xb, ap, acc);
    conv_seg<3,2>( 65,  77, xb, ap, acc);
    conv_seg<4,2>( 77,  83, xb, ap, acc);
    conv_seg<5,2>( 83,  85, xb, ap, acc);
    conv_seg<4,2>( 85,  92, xb, ap, acc);
    conv_seg<3,2>( 92, 104, xb, ap, acc);
    conv_seg<2,3>(104, 127, xb, ap, acc);
    conv_seg<1,5>(127, 169, xb, ap, acc);

    // ---- fused epilogue: D col=lane&15 -> A-col n, row=grp*4+r -> b ----
    // t = 1024w + 256j + 16*(lane&15) + 4*grp + r; out[n][t][c][s]: 5 floats
    // contiguous at ((n*2048+t)*64+c)*5. Exec sl -> output s = 4-sl.
    #pragma unroll
    for (int j = 0; j < 4; ++j) {
        #pragma unroll
        for (int r = 0; r < 4; ++r) {
            const int t = 1024 * w + 256 * j + 16 * mcol + 4 * grp + r;
            float* ob = out + ((size_t)((nidx * 2048 + t) * 64 + cidx)) * 5;
            ob[4] = acc[0][j][r];
            ob[3] = acc[1][j][r];
            ob[2] = acc[2][j][r];
            ob[1] = acc[3][j][r];
            ob[0] = acc[4][j][r];
        }
    }
}

// ---------------- launch ----------------
extern "C" void kernel_launch(void* const* d_in, const int* in_sizes, int n_in,
                              void* d_out, int out_size, void* d_ws, size_t ws_size,
                              hipStream_t stream) {
    const float* x = (const float*)d_in[0];
    float* out = (float*)d_out;
    char* ws = (char*)d_ws;

    __half* W    = (__half*)ws;
    __half* xT   = (__half*)(ws + WS_XT);

    cwt_prep<<<129, 1024, 0, stream>>>(x, xT, W);
    cwt_conv_mfma<<<NROWS, 128, 0, stream>>>(xT, W, out);
}